// Round 11
// baseline (100.356 us; speedup 1.0000x reference)
//
#include <hip/hip_runtime.h>

typedef _Float16 half8 __attribute__((ext_vector_type(8)));
typedef float f32x4 __attribute__((ext_vector_type(4)));

#define DD 128

// Workspace layout (R2-verified):
//   FRAG: nch records of 8192 B. Record c, octet idx=(s*2+hl) in 0..7 at
//         offset idx*1024 + lane*16: 8 f16 of code n=c*16+(lane&15),
//         k = s*32 + (lane>>4)*8 + 0..7.  hl=0 -> hi, hl=1 -> lo.
//   E2NEG: nch*256 B after FRAG; wse[c*64 + j] = -||e_{c*16+(j&15)}||^2.

__global__ void prep_kernel(const float* __restrict__ embed,
                            char* __restrict__ frag,
                            float* __restrict__ e2neg, int total) {
  int t = blockIdx.x * blockDim.x + threadIdx.x;
  if (t >= total) return;
  int lane = t & 63;
  int idx = (t >> 6) & 7;
  int c = t >> 9;
  int s = idx >> 1;
  int hl = idx & 1;
  int n = c * 16 + (lane & 15);
  int kb = s * 32 + ((lane >> 4) << 3);
  const float* src = embed + (size_t)n * DD + kb;
  _Float16* dst = (_Float16*)(frag + (size_t)c * 8192 + idx * 1024 + lane * 16);
#pragma unroll
  for (int j = 0; j < 8; ++j) {
    float v = src[j];
    _Float16 hi = (_Float16)v;
    dst[j] = hl ? (_Float16)(v - (float)hi) : hi;
  }
  if (idx == 0) {
    const float* e = embed + (size_t)n * DD;
    double acc = 0.0;
    for (int j = 0; j < DD; ++j) { double v = (double)e[j]; acc += v * v; }
    e2neg[c * 64 + lane] = (float)(-acc);
  }
}

// ---------------------------------------------------------------------------
// WAVE-SPECIALIZED main (simplified): block = 384 thr (6 waves), 128 rows.
// Waves 0..3 = producers (32 rows each): R2-VERBATIM loop (register ping-pong
// B prefetch from L2, 24x mfma_f32_16x16x32_f16, bit-identical scores) — but
// the argmax epilogue is replaced by TWO swizzled ds_write_b128 of raw acc.
// Waves 4..5 = consumers: ONE row per lane; per chunk scan 16 codes ascending
// (fmaf(2,acc,-e2), strict > => first-max ties), e2 from a block-start LDS
// table. Cross-wave MFMA/VALU overlap per m114; in-wave it doesn't happen
// (m253) — that was the measured 24us epilogue cost (abl2=38 vs V0=62).
// Score LDS layout: [buf][code k][row r] f32, byte = (k<<9) +
// (((r*4)&~15) ^ (k<<4)) + ((r*4)&12)  — XOR keeps writes 16B-aligned and
// spreads the 16-lane same-code column across banks. Two barriers per
// 2-chunk iteration; all waves execute identical barrier counts.
// C/D layout (verified): col=lane&15, row=(lane>>4)*4+reg.
// ---------------------------------------------------------------------------
__global__ __launch_bounds__(384) void vq_argmin_kernel(
    const float* __restrict__ x, const float* __restrict__ embed,
    const char* __restrict__ wsf, const float* __restrict__ wse,
    float* __restrict__ out_q, float* __restrict__ out_i, int nch) {
  const int tid = threadIdx.x;
  const int lane = tid & 63;
  const int w = tid >> 6;
  const int m16 = lane & 15;
  const int g = lane >> 4;
  const int blk_row0 = blockIdx.x * 128;

  __shared__ alignas(16) char sbuf[2][8192];  // scores, swizzled [code][row]
  __shared__ float lds_e2[1024];              // -||e||^2, dedup (nch<=64)
  __shared__ int idxbuf[128];

  // e2 table -> LDS once (all 384 threads)
  for (int i = tid; i < nch * 16; i += 384)
    lds_e2[i] = wse[(size_t)(i >> 4) * 64 + (i & 15)];

  // ---- producer state (R2-verbatim registers) ----
  half8 ah[2][4], al[2][4];
  half8 bhA[4], blA[4], bhB[4], blB[4];
  // ---- consumer state: one row per lane ----
  const int crow = ((w & 1) << 6) | lane;  // w=4 -> rows 0..63, w=5 -> 64..127
  const int rb_hi = (crow << 2) & 0x1F0;
  const int rb_lo = (crow << 2) & 12;
  float bestv = -__builtin_inff();
  int besti = 0;

#define LOADB(BH, BL, C)                                            \
  do {                                                              \
    const char* pf = wsf + (size_t)(C)*8192 + lane * 16;            \
    const char* pf1 = pf + 4096;                                    \
    BH[0] = *(const half8*)(pf);                                    \
    BL[0] = *(const half8*)(pf + 1024);                             \
    BH[1] = *(const half8*)(pf + 2048);                             \
    BL[1] = *(const half8*)(pf + 3072);                             \
    BH[2] = *(const half8*)(pf1);                                   \
    BL[2] = *(const half8*)(pf1 + 1024);                            \
    BH[3] = *(const half8*)(pf1 + 2048);                            \
    BL[3] = *(const half8*)(pf1 + 3072);                            \
  } while (0)

  // R2-verbatim MFMA chains; epilogue = two swizzled b128 score writes.
#define COMPUTE(BH, BL, BUF)                                                 \
  do {                                                                       \
    f32x4 acc0 = {0.f, 0.f, 0.f, 0.f};                                       \
    f32x4 acc1 = {0.f, 0.f, 0.f, 0.f};                                       \
    _Pragma("unroll") for (int s = 0; s < 4; ++s) {                          \
      acc0 = __builtin_amdgcn_mfma_f32_16x16x32_f16(ah[0][s], BH[s], acc0,   \
                                                    0, 0, 0);                \
      acc1 = __builtin_amdgcn_mfma_f32_16x16x32_f16(ah[1][s], BH[s], acc1,   \
                                                    0, 0, 0);                \
      acc0 = __builtin_amdgcn_mfma_f32_16x16x32_f16(al[0][s], BH[s], acc0,   \
                                                    0, 0, 0);                \
      acc1 = __builtin_amdgcn_mfma_f32_16x16x32_f16(al[1][s], BH[s], acc1,   \
                                                    0, 0, 0);                \
      acc0 = __builtin_amdgcn_mfma_f32_16x16x32_f16(ah[0][s], BL[s], acc0,   \
                                                    0, 0, 0);                \
      acc1 = __builtin_amdgcn_mfma_f32_16x16x32_f16(ah[1][s], BL[s], acc1,   \
                                                    0, 0, 0);                \
    }                                                                        \
    const int lr0_ = (w << 5) + (g << 2);                                    \
    const int lr1_ = lr0_ + 16;                                              \
    char* sb_ = &sbuf[BUF][m16 << 9];                                        \
    *(f32x4*)(sb_ + ((lr0_ << 2) ^ (m16 << 4))) = acc0;                      \
    *(f32x4*)(sb_ + ((lr1_ << 2) ^ (m16 << 4))) = acc1;                      \
  } while (0)

  // consumer: argmax of chunk CC from sbuf[CC&1]; ascending k => first-max.
#define ARGMAX(CC)                                                           \
  do {                                                                       \
    const int cc_ = (CC);                                                    \
    const char* sb_ = &sbuf[cc_ & 1][0];                                     \
    _Pragma("unroll") for (int k = 0; k < 16; ++k) {                         \
      float sv = *(const float*)(sb_ + (k << 9) + ((rb_hi ^ (k << 4)) | rb_lo)); \
      float sc = fmaf(2.f, sv, lds_e2[cc_ * 16 + k]);                        \
      if (sc > bestv) { bestv = sc; besti = cc_ * 16 + k; }                  \
    }                                                                        \
  } while (0)

  if (w < 4) {
    // A fragments (R2-verbatim): rows blk_row0 + w*32 .. +31, 2 tiles
    const int row0 = blk_row0 + w * 32;
#pragma unroll
    for (int t = 0; t < 2; ++t) {
      const float* xrow = x + (size_t)(row0 + t * 16 + m16) * DD;
#pragma unroll
      for (int s = 0; s < 4; ++s) {
        const float* p = xrow + s * 32 + g * 8;
        f32x4 v0 = *(const f32x4*)(p);
        f32x4 v1 = *(const f32x4*)(p + 4);
#pragma unroll
        for (int j = 0; j < 4; ++j) {
          float v = v0[j];
          _Float16 hi = (_Float16)v;
          ah[t][s][j] = hi;
          al[t][s][j] = (_Float16)(v - (float)hi);
        }
#pragma unroll
        for (int j = 0; j < 4; ++j) {
          float v = v1[j];
          _Float16 hi = (_Float16)v;
          ah[t][s][4 + j] = hi;
          al[t][s][4 + j] = (_Float16)(v - (float)hi);
        }
      }
    }
    LOADB(bhA, blA, 0);
  }
  __syncthreads();  // e2 table + nothing else pending for consumers

  for (int c = 0; c < nch; c += 2) {
    // ---- phase 1: producers compute chunk c -> sbuf[0]; consumers argmax
    //      chunk c-1 from sbuf[1] ----
    if (w < 4) {
      LOADB(bhB, blB, c + 1);
      COMPUTE(bhA, blA, 0);
    } else if (c) {
      ARGMAX(c - 1);
    }
    __syncthreads();
    // ---- phase 2: producers compute chunk c+1 -> sbuf[1]; consumers argmax
    //      chunk c from sbuf[0] ----
    if (w < 4) {
      if (c + 2 < nch) LOADB(bhA, blA, c + 2);
      COMPUTE(bhB, blB, 1);
    } else {
      ARGMAX(c);
    }
    __syncthreads();
  }
#undef LOADB
#undef COMPUTE

  // final chunk (nch-1, odd -> sbuf[1]); producers just pass through
  if (w >= 4) {
    ARGMAX(nch - 1);
    idxbuf[crow] = besti;
  }
#undef ARGMAX
  __syncthreads();

  // outputs: indices + cooperative gather (12 half-waves x 32 lanes x 16B)
  if (tid < 128) out_i[blk_row0 + tid] = (float)idxbuf[tid];
  const int hw = tid >> 5;
  const int l32 = tid & 31;
  for (int r = hw; r < 128; r += 12) {
    const int idx = idxbuf[r];
    f32x4 v = *((const f32x4*)(embed + (size_t)idx * DD) + l32);
    *((f32x4*)(out_q + (size_t)(blk_row0 + r) * DD) + l32) = v;
  }
}

// ---------------------------------------------------------------------------
// Fallback: exact double-precision distance, thread per row.
// ---------------------------------------------------------------------------
__global__ void vq_fallback_kernel(const float* __restrict__ x,
                                   const float* __restrict__ embed,
                                   float* __restrict__ out_q,
                                   float* __restrict__ out_i, int N, int K) {
  int row = blockIdx.x * blockDim.x + threadIdx.x;
  if (row >= N) return;
  const float* xr = x + (size_t)row * DD;
  float xv[DD];
  for (int j = 0; j < DD; ++j) xv[j] = xr[j];
  double best = -1e300;
  int bi = 0;
  for (int k = 0; k < K; ++k) {
    const float* e = embed + (size_t)k * DD;
    double acc = 0.0;
    for (int j = 0; j < DD; ++j) {
      double d = (double)xv[j] - (double)e[j];
      acc += d * d;
    }
    double sc = -acc;
    if (sc > best) { best = sc; bi = k; }
  }
  out_i[row] = (float)bi;
  for (int j = 0; j < DD; ++j)
    out_q[(size_t)row * DD + j] = embed[(size_t)bi * DD + j];
}

extern "C" void kernel_launch(void* const* d_in, const int* in_sizes, int n_in,
                              void* d_out, int out_size, void* d_ws,
                              size_t ws_size, hipStream_t stream) {
  const float* x = (const float*)d_in[0];
  const float* embed = (const float*)d_in[1];
  const int N = in_sizes[0] / DD;  // 65536 rows
  const int K = in_sizes[1] / DD;  // 1024 codes
  float* out_q = (float*)d_out;
  float* out_i = out_q + (size_t)N * DD;

  const int nch = K / 16;
  const size_t frag_bytes = (size_t)nch * 8192;
  const size_t e2_bytes = (size_t)nch * 256;
  const size_t need = frag_bytes + e2_bytes;

  if (ws_size < need || (N % 128) != 0 || (K % 16) != 0 || (nch % 2) != 0 ||
      nch < 2 || nch > 64) {
    vq_fallback_kernel<<<(N + 255) / 256, 256, 0, stream>>>(x, embed, out_q,
                                                            out_i, N, K);
    return;
  }

  char* wsf = (char*)d_ws;
  float* wse = (float*)(wsf + frag_bytes);

  const int total_f = nch * 8 * 64;
  prep_kernel<<<(total_f + 255) / 256, 256, 0, stream>>>(embed, wsf, wse,
                                                         total_f);
  vq_argmin_kernel<<<N / 128, 384, 0, stream>>>(x, embed, wsf, wse, out_q,
                                                out_i, nch);
}

// Round 12
// 65.285 us; speedup vs baseline: 1.5372x; 1.5372x over previous
//
#include <hip/hip_runtime.h>

typedef _Float16 half8 __attribute__((ext_vector_type(8)));
typedef float f32x4 __attribute__((ext_vector_type(4)));

#define DD 128

// Workspace layout (R2-verified):
//   FRAG: nch records of 8192 B. Record c, octet idx=(s*2+hl) in 0..7 at
//         offset idx*1024 + lane*16: 8 f16 of code n=c*16+(lane&15),
//         k = s*32 + (lane>>4)*8 + 0..7.  hl=0 -> hi, hl=1 -> lo.
//   E2NEG: nch*256 B after FRAG; wse[c*64 + j] = -||e_{c*16+(j&15)}||^2.

__global__ void prep_kernel(const float* __restrict__ embed,
                            char* __restrict__ frag,
                            float* __restrict__ e2neg, int total) {
  int t = blockIdx.x * blockDim.x + threadIdx.x;
  if (t >= total) return;
  int lane = t & 63;
  int idx = (t >> 6) & 7;
  int c = t >> 9;
  int s = idx >> 1;
  int hl = idx & 1;
  int n = c * 16 + (lane & 15);
  int kb = s * 32 + ((lane >> 4) << 3);
  const float* src = embed + (size_t)n * DD + kb;
  _Float16* dst = (_Float16*)(frag + (size_t)c * 8192 + idx * 1024 + lane * 16);
#pragma unroll
  for (int j = 0; j < 8; ++j) {
    float v = src[j];
    _Float16 hi = (_Float16)v;
    dst[j] = hl ? (_Float16)(v - (float)hi) : hi;
  }
  if (idx == 0) {
    const float* e = embed + (size_t)n * DD;
    double acc = 0.0;
    for (int j = 0; j < DD; ++j) { double v = (double)e[j]; acc += v * v; }
    e2neg[c * 64 + lane] = (float)(-acc);
  }
}

// ---------------------------------------------------------------------------
// Main: R2 skeleton (block = 256 thr / 4 waves, wave owns 32 rows, register
// ping-pong B prefetch, 24x mfma_f32_16x16x32_f16 per chunk, bit-identical
// scores) with a 4-DEEP ROTATED ACCUMULATOR PIPELINE: chunk c's argmax
// epilogue executes after chunk c+2's MFMAs are issued, on its own acc set
// (P0..P3, named — no runtime indexing). This removes the per-chunk WAR +
// chain-drain stall that R7's ablation isolated (abl2 38us vs V0 62us):
// in-order issue meant EPI waited out the full 12-deep MFMA chain latency
// and the next chunk's MFMAs waited on EPI's acc reads. EPI order remains
// ascending chunks -> exact first-max tie semantics.
// C/D layout (verified): col=lane&15, row=(lane>>4)*4+reg.
// ---------------------------------------------------------------------------
__global__ __launch_bounds__(256) void vq_argmin_kernel(
    const float* __restrict__ x, const float* __restrict__ embed,
    const char* __restrict__ wsf, const float* __restrict__ wse,
    float* __restrict__ out_q, float* __restrict__ out_i, int nch) {
  const int lane = threadIdx.x & 63;
  const int w = threadIdx.x >> 6;
  const int m16 = lane & 15;
  const int g = lane >> 4;
  const int row0 = blockIdx.x * 128 + w * 32;

  // A fragments for 2 row-tiles, f16 hi/lo split (R2-verbatim)
  half8 ah[2][4], al[2][4];
#pragma unroll
  for (int t = 0; t < 2; ++t) {
    const float* xrow = x + (size_t)(row0 + t * 16 + m16) * DD;
#pragma unroll
    for (int s = 0; s < 4; ++s) {
      const float* p = xrow + s * 32 + g * 8;
      f32x4 v0 = *(const f32x4*)(p);
      f32x4 v1 = *(const f32x4*)(p + 4);
#pragma unroll
      for (int j = 0; j < 4; ++j) {
        float v = v0[j];
        _Float16 hi = (_Float16)v;
        ah[t][s][j] = hi;
        al[t][s][j] = (_Float16)(v - (float)hi);
      }
#pragma unroll
      for (int j = 0; j < 4; ++j) {
        float v = v1[j];
        _Float16 hi = (_Float16)v;
        ah[t][s][4 + j] = hi;
        al[t][s][4 + j] = (_Float16)(v - (float)hi);
      }
    }
  }

  float bestv0[4], bestv1[4];
  int besti0[4], besti1[4];
#pragma unroll
  for (int r = 0; r < 4; ++r) {
    bestv0[r] = -__builtin_inff();
    bestv1[r] = -__builtin_inff();
    besti0[r] = 0;
    besti1[r] = 0;
  }

  half8 bhA[4], blA[4], bhB[4], blB[4];
  float ne0, ne1, ne2, ne3;
  f32x4 p0a, p0b, p1a, p1b, p2a, p2b, p3a, p3b;  // acc sets P0..P3 (2 tiles)

#define LOADB(BH, BL, NE, C)                                        \
  do {                                                              \
    const char* pf = wsf + (size_t)(C)*8192 + lane * 16;            \
    const char* pf1 = pf + 4096;                                    \
    BH[0] = *(const half8*)(pf);                                    \
    BL[0] = *(const half8*)(pf + 1024);                             \
    BH[1] = *(const half8*)(pf + 2048);                             \
    BL[1] = *(const half8*)(pf + 3072);                             \
    BH[2] = *(const half8*)(pf1);                                   \
    BL[2] = *(const half8*)(pf1 + 1024);                            \
    BH[3] = *(const half8*)(pf1 + 2048);                            \
    BL[3] = *(const half8*)(pf1 + 3072);                            \
    NE = wse[(size_t)(C)*64 + lane];                                \
  } while (0)

  // R2-verbatim chains into acc set (ACC0, ACC1), zero-initialized here.
#define MFMA_CHUNK(ACC0, ACC1, BH, BL)                                       \
  do {                                                                       \
    ACC0 = f32x4{0.f, 0.f, 0.f, 0.f};                                        \
    ACC1 = f32x4{0.f, 0.f, 0.f, 0.f};                                        \
    _Pragma("unroll") for (int s = 0; s < 4; ++s) {                          \
      ACC0 = __builtin_amdgcn_mfma_f32_16x16x32_f16(ah[0][s], BH[s], ACC0,   \
                                                    0, 0, 0);                \
      ACC1 = __builtin_amdgcn_mfma_f32_16x16x32_f16(ah[1][s], BH[s], ACC1,   \
                                                    0, 0, 0);                \
      ACC0 = __builtin_amdgcn_mfma_f32_16x16x32_f16(al[0][s], BH[s], ACC0,   \
                                                    0, 0, 0);                \
      ACC1 = __builtin_amdgcn_mfma_f32_16x16x32_f16(al[1][s], BH[s], ACC1,   \
                                                    0, 0, 0);                \
      ACC0 = __builtin_amdgcn_mfma_f32_16x16x32_f16(ah[0][s], BL[s], ACC0,   \
                                                    0, 0, 0);                \
      ACC1 = __builtin_amdgcn_mfma_f32_16x16x32_f16(ah[1][s], BL[s], ACC1,   \
                                                    0, 0, 0);                \
    }                                                                        \
  } while (0)

  // R2-verbatim epilogue on acc set; ascending-chunk call order.
#define EPI(ACC0, ACC1, NE, C)                                               \
  do {                                                                       \
    const int n_ = (C)*16 + m16;                                             \
    _Pragma("unroll") for (int r = 0; r < 4; ++r) {                          \
      float s0 = fmaf(2.f, ACC0[r], NE);                                     \
      if (s0 > bestv0[r]) { bestv0[r] = s0; besti0[r] = n_; }                \
      float s1 = fmaf(2.f, ACC1[r], NE);                                     \
      if (s1 > bestv1[r]) { bestv1[r] = s1; besti1[r] = n_; }                \
    }                                                                        \
  } while (0)

  // ---- group 0 peeled (no EPI for negative chunks) ----
  LOADB(bhA, blA, ne0, 0);
  LOADB(bhB, blB, ne1, 1);
  MFMA_CHUNK(p0a, p0b, bhA, blA);
  LOADB(bhA, blA, ne2, 2);
  MFMA_CHUNK(p1a, p1b, bhB, blB);
  LOADB(bhB, blB, ne3, 3);
  MFMA_CHUNK(p2a, p2b, bhA, blA);
  EPI(p0a, p0b, ne0, 0);
  if (4 < nch) LOADB(bhA, blA, ne0, 4);
  MFMA_CHUNK(p3a, p3b, bhB, blB);
  EPI(p1a, p1b, ne1, 1);

  // ---- steady state: groups g >= 1 ----
  for (int c = 4; c < nch; c += 4) {
    LOADB(bhB, blB, ne1, c + 1);
    MFMA_CHUNK(p0a, p0b, bhA, blA);  // chunk c
    EPI(p2a, p2b, ne2, c - 2);
    LOADB(bhA, blA, ne2, c + 2);
    MFMA_CHUNK(p1a, p1b, bhB, blB);  // chunk c+1
    EPI(p3a, p3b, ne3, c - 1);
    LOADB(bhB, blB, ne3, c + 3);
    MFMA_CHUNK(p2a, p2b, bhA, blA);  // chunk c+2
    EPI(p0a, p0b, ne0, c);
    if (c + 4 < nch) LOADB(bhA, blA, ne0, c + 4);
    MFMA_CHUNK(p3a, p3b, bhB, blB);  // chunk c+3
    EPI(p1a, p1b, ne1, c + 1);
  }
  // tail
  EPI(p2a, p2b, ne2, nch - 2);
  EPI(p3a, p3b, ne3, nch - 1);
#undef LOADB
#undef MFMA_CHUNK
#undef EPI

  // reduce across the 16 lanes sharing each C row; smaller index on tie
#pragma unroll
  for (int off = 1; off < 16; off <<= 1) {
#pragma unroll
    for (int r = 0; r < 4; ++r) {
      float ov0 = __shfl_xor(bestv0[r], off, 64);
      int oi0 = __shfl_xor(besti0[r], off, 64);
      if (ov0 > bestv0[r] || (ov0 == bestv0[r] && oi0 < besti0[r])) {
        bestv0[r] = ov0;
        besti0[r] = oi0;
      }
      float ov1 = __shfl_xor(bestv1[r], off, 64);
      int oi1 = __shfl_xor(besti1[r], off, 64);
      if (ov1 > bestv1[r] || (ov1 == bestv1[r] && oi1 < besti1[r])) {
        bestv1[r] = ov1;
        besti1[r] = oi1;
      }
    }
  }

  // outputs: index (as float) + gathered code row (16 lanes x 8 floats)
#pragma unroll
  for (int t = 0; t < 2; ++t) {
#pragma unroll
    for (int r = 0; r < 4; ++r) {
      const int row = row0 + t * 16 + g * 4 + r;
      const int idx = t ? besti1[r] : besti0[r];
      if (m16 == 0) out_i[row] = (float)idx;
      const f32x4* src = (const f32x4*)(embed + (size_t)idx * DD) + m16 * 2;
      f32x4* dst = (f32x4*)(out_q + (size_t)row * DD) + m16 * 2;
      dst[0] = src[0];
      dst[1] = src[1];
    }
  }
}

// ---------------------------------------------------------------------------
// Fallback: exact double-precision distance, thread per row.
// ---------------------------------------------------------------------------
__global__ void vq_fallback_kernel(const float* __restrict__ x,
                                   const float* __restrict__ embed,
                                   float* __restrict__ out_q,
                                   float* __restrict__ out_i, int N, int K) {
  int row = blockIdx.x * blockDim.x + threadIdx.x;
  if (row >= N) return;
  const float* xr = x + (size_t)row * DD;
  float xv[DD];
  for (int j = 0; j < DD; ++j) xv[j] = xr[j];
  double best = -1e300;
  int bi = 0;
  for (int k = 0; k < K; ++k) {
    const float* e = embed + (size_t)k * DD;
    double acc = 0.0;
    for (int j = 0; j < DD; ++j) {
      double d = (double)xv[j] - (double)e[j];
      acc += d * d;
    }
    double sc = -acc;
    if (sc > best) { best = sc; bi = k; }
  }
  out_i[row] = (float)bi;
  for (int j = 0; j < DD; ++j)
    out_q[(size_t)row * DD + j] = embed[(size_t)bi * DD + j];
}

extern "C" void kernel_launch(void* const* d_in, const int* in_sizes, int n_in,
                              void* d_out, int out_size, void* d_ws,
                              size_t ws_size, hipStream_t stream) {
  const float* x = (const float*)d_in[0];
  const float* embed = (const float*)d_in[1];
  const int N = in_sizes[0] / DD;  // 65536 rows
  const int K = in_sizes[1] / DD;  // 1024 codes
  float* out_q = (float*)d_out;
  float* out_i = out_q + (size_t)N * DD;

  const int nch = K / 16;
  const size_t frag_bytes = (size_t)nch * 8192;
  const size_t e2_bytes = (size_t)nch * 256;
  const size_t need = frag_bytes + e2_bytes;

  if (ws_size < need || (N % 128) != 0 || (K % 16) != 0 || (nch % 4) != 0 ||
      nch < 8) {
    vq_fallback_kernel<<<(N + 255) / 256, 256, 0, stream>>>(x, embed, out_q,
                                                            out_i, N, K);
    return;
  }

  char* wsf = (char*)d_ws;
  float* wse = (float*)(wsf + frag_bytes);

  const int total_f = nch * 8 * 64;
  prep_kernel<<<(total_f + 255) / 256, 256, 0, stream>>>(embed, wsf, wse,
                                                         total_f);
  vq_argmin_kernel<<<N / 128, 256, 0, stream>>>(x, embed, wsf, wse, out_q,
                                                out_i, nch);
}